// Round 1
// baseline (2770.068 us; speedup 1.0000x reference)
//
#include <hip/hip_runtime.h>
#include <hip/hip_cooperative_groups.h>
#include <math.h>

namespace cg = cooperative_groups;

#define N_ 50000
#define K_ 64
#define M_ 64
#define MAXIT 40
#define NBLK 196      // ceil(50000/256)
#define BSZ 256

#define CG_TOLf  1e-6f
#define CG_REGf  1e-8f
#define TOL_ABSf 1e-14f

// ---- workspace layout (float offsets) ----
#define OFF_AAT   0          // 64x64
#define OFF_INV   4096       // 64x64
#define OFF_W     8192       // w = U^T p   (64)
#define OFF_Y     8256       // y = A r     (64)
#define OFF_HZ    8320       // Hz dots     (64, 41 used)
#define OFF_PHPD  8384       // pHp_diag    (40)
#define OFF_SCAL  8424       // [0]pHp [1]pp [2]rp [3]rz [4]rz_new [5]zz [6]pgn2 [7]conv
#define WS_SMALL  8448
#define OFF_UT    WS_SMALL                 // K x N transposed U
#define OFF_P     (OFF_UT + K_ * N_)       // 40 x N search dirs
#define OFF_HP    (OFF_P + MAXIT * N_)     // 40 x N H*p history

__device__ __forceinline__ float wave_reduce_sum(float v) {
#pragma unroll
  for (int m = 1; m < 64; m <<= 1) v += __shfl_xor(v, m, 64);
  return v;
}

__global__ __launch_bounds__(BSZ)
void stcg_kernel(const float* __restrict__ g, const float* __restrict__ dg,
                 const float* __restrict__ U, const float* __restrict__ A,
                 float* __restrict__ out, float* __restrict__ ws)
{
  cg::grid_group grid = cg::this_grid();
  const int b = blockIdx.x, t = threadIdx.x;
  const int wv = t >> 6, lane = t & 63;
  const int base = b * BSZ;
  const int i = base + t;
  const bool valid = i < N_;

  float* AAt  = ws + OFF_AAT;
  float* inv  = ws + OFF_INV;
  float* wacc = ws + OFF_W;
  float* yacc = ws + OFF_Y;
  float* Hz   = ws + OFF_HZ;
  float* pHpd = ws + OFF_PHPD;
  float* scl  = ws + OFF_SCAL;
  float* Ut   = ws + OFF_UT;
  float* Pb   = ws + OFF_P;
  float* HPb  = ws + OFF_HP;

  __shared__ float aug[64 * 132];   // GJ augmented matrix; reused as 64x65 tile in I1
  __shared__ float stage[BSZ];
  __shared__ float wsh[64];
  __shared__ float ssh[64];
  __shared__ float csh[64];
  __shared__ float ysh[64];
  __shared__ float fsh[64];
  __shared__ float rowk[128];
  __shared__ float red[8];
  __shared__ float scal[8];

  // ---------------- I0: zero small accumulators; transpose U ----------------
  {
    if (i < WS_SMALL) ws[i] = 0.0f;
    if (valid) {
      const float4* U4 = (const float4*)(U + (size_t)i * K_);
#pragma unroll
      for (int k4 = 0; k4 < K_ / 4; ++k4) {
        float4 u = U4[k4];
        Ut[(size_t)(4 * k4 + 0) * N_ + i] = u.x;
        Ut[(size_t)(4 * k4 + 1) * N_ + i] = u.y;
        Ut[(size_t)(4 * k4 + 2) * N_ + i] = u.z;
        Ut[(size_t)(4 * k4 + 3) * N_ + i] = u.w;
      }
    }
  }
  grid.sync();

  // ---------------- I1: AAt partials (LDS tile, 4x4 reg blocking) + y0 = A*g ----------------
  {
    float* tile = aug;  // 64 x 65 view
    float acc[4][4];
#pragma unroll
    for (int a = 0; a < 4; ++a)
#pragma unroll
      for (int c = 0; c < 4; ++c) acc[a][c] = 0.0f;
    const int tr4 = (t >> 4) << 2;
    const int tc4 = (t & 15) << 2;
    for (int sub = 0; sub < 4; ++sub) {
      const int cb = base + (sub << 6);
      __syncthreads();
      for (int r = wv; r < 64; r += 4) {
        const int col = cb + lane;
        tile[r * 65 + lane] = (col < N_) ? A[(size_t)r * N_ + col] : 0.0f;
      }
      __syncthreads();
#pragma unroll 4
      for (int j = 0; j < 64; ++j) {
        float a0 = tile[(tr4 + 0) * 65 + j];
        float a1 = tile[(tr4 + 1) * 65 + j];
        float a2 = tile[(tr4 + 2) * 65 + j];
        float a3 = tile[(tr4 + 3) * 65 + j];
        float b0 = tile[(tc4 + 0) * 65 + j];
        float b1 = tile[(tc4 + 1) * 65 + j];
        float b2 = tile[(tc4 + 2) * 65 + j];
        float b3 = tile[(tc4 + 3) * 65 + j];
        acc[0][0] += a0 * b0; acc[0][1] += a0 * b1; acc[0][2] += a0 * b2; acc[0][3] += a0 * b3;
        acc[1][0] += a1 * b0; acc[1][1] += a1 * b1; acc[1][2] += a1 * b2; acc[1][3] += a1 * b3;
        acc[2][0] += a2 * b0; acc[2][1] += a2 * b1; acc[2][2] += a2 * b2; acc[2][3] += a2 * b3;
        acc[3][0] += a3 * b0; acc[3][1] += a3 * b1; acc[3][2] += a3 * b2; acc[3][3] += a3 * b3;
      }
    }
#pragma unroll
    for (int a = 0; a < 4; ++a)
#pragma unroll
      for (int c = 0; c < 4; ++c)
        atomicAdd(&AAt[(tr4 + a) * 64 + (tc4 + c)], acc[a][c]);

    __syncthreads();
    stage[t] = valid ? g[i] : 0.0f;
    __syncthreads();
    for (int m = wv; m < M_; m += 4) {
      float s = 0.0f;
#pragma unroll
      for (int e0 = 0; e0 < BSZ; e0 += 64) {
        const int e = e0 + lane, col = base + e;
        const float av = (col < N_) ? A[(size_t)m * N_ + col] : 0.0f;
        s += av * stage[e];
      }
      s = wave_reduce_sum(s);
      if (lane == 0) atomicAdd(&yacc[m], s);
    }
  }
  grid.sync();

  // ---------------- I2: Gauss-Jordan inverse of (AAt + 1e-8 I) on block 0 ----------------
  if (b == 0) {
    for (int idx = t; idx < 64 * 128; idx += BSZ) {
      const int r = idx >> 7, c = idx & 127;
      float v;
      if (c < 64) v = AAt[r * 64 + c] + ((r == c) ? 1e-8f : 0.0f);
      else        v = ((c - 64) == r) ? 1.0f : 0.0f;
      aug[r * 132 + c] = v;
    }
    __syncthreads();
    for (int k = 0; k < 64; ++k) {
      if (t < 128) rowk[t] = aug[k * 132 + t];
      __syncthreads();
      const float pivinv = 1.0f / rowk[k];
      if (t < 64) fsh[t] = (t == k) ? 0.0f : aug[t * 132 + k] * pivinv;
      __syncthreads();
      for (int idx = t; idx < 64 * 128; idx += BSZ) {
        const int r = idx >> 7, c = idx & 127;
        const float rk = rowk[c] * pivinv;
        aug[r * 132 + c] = (r == k) ? rk : (aug[r * 132 + c] - fsh[r] * rk);
      }
      __syncthreads();
    }
    for (int idx = t; idx < 64 * 64; idx += BSZ) {
      const int r = idx >> 6, c = idx & 63;
      inv[r * 64 + c] = aug[r * 132 + 64 + c];
    }
  }
  grid.sync();

  // ---------------- I3: r0 = A^T s0 - g; init regs; rz0(=pp=rp); w = U^T p0 ----------------
  float t_ = 0.0f, r_ = 0.0f, p_ = 0.0f, z_ = 0.0f, hp_ = 0.0f;
  {
    if (t < 64) ysh[t] = yacc[t];
    __syncthreads();
    if (t < 64) {
      float s = 0.0f;
#pragma unroll 8
      for (int j = 0; j < 64; ++j) s += inv[t * 64 + j] * ysh[j];
      ssh[t] = s;
    }
    __syncthreads();
    if (valid) {
      float acc = 0.0f;
#pragma unroll 8
      for (int m = 0; m < M_; ++m) acc += A[(size_t)m * N_ + i] * ssh[m];
      const float r0 = acc - g[i];   // -(g - A^T s0)
      r_ = r0; p_ = r0; z_ = r0;
    }
    stage[t] = valid ? r_ : 0.0f;
    float v = wave_reduce_sum(r_ * r_);
    if (lane == 0) red[wv] = v;
    __syncthreads();
    if (t == 0) {
      const float s = red[0] + red[1] + red[2] + red[3];
      atomicAdd(&scl[3], s);  // rz
      atomicAdd(&scl[1], s);  // pp
      atomicAdd(&scl[2], s);  // rp
    }
    __syncthreads();
    for (int k = wv; k < K_; k += 4) {
      float s = 0.0f;
#pragma unroll
      for (int e0 = 0; e0 < BSZ; e0 += 64) {
        const int e = e0 + lane, col = base + e;
        const float uv = (col < N_) ? Ut[(size_t)k * N_ + col] : 0.0f;
        s += uv * stage[e];
      }
      s = wave_reduce_sum(s);
      if (lane == 0) atomicAdd(&wacc[k], s);
    }
  }
  grid.sync();

  // ---------------- main CG loop ----------------
  float pgn2_r = 0.0f;
  bool sc_r = false;
  for (int it = 0; it < MAXIT; ++it) {
    // converged? (uniform: single writer + grid.sync before this read)
    const float convf = __hip_atomic_load(&scl[7], __ATOMIC_ACQUIRE, __HIP_MEMORY_SCOPE_AGENT);
    if (convf != 0.0f) break;

    // ---- A: Hp = diag*p + U (U^T p); pHp; zero y; publish pgn2 at it==0 ----
    if (b == 0) {
      if (t < 64) yacc[t] = 0.0f;
      if (t == 64 && it == 0) scl[6] = scl[3];  // pgn2 = rz0
    }
    if (t < 64) wsh[t] = wacc[t];
    __syncthreads();
    float hp = 0.0f;
    if (valid) {
      hp = dg[i] * p_;
#pragma unroll 8
      for (int k = 0; k < K_; ++k) hp += Ut[(size_t)k * N_ + i] * wsh[k];
      HPb[(size_t)it * N_ + i] = hp;
      Pb[(size_t)it * N_ + i]  = p_;
    }
    hp_ = hp;
    {
      const float v = wave_reduce_sum(p_ * hp);
      if (lane == 0) red[wv] = v;
      __syncthreads();
      if (t == 0) atomicAdd(&scl[0], red[0] + red[1] + red[2] + red[3]);
    }
    grid.sync();

    // ---- B: alpha; t,r update; y = A r_new; zero zz/rz_new/Hz; store pHp_diag ----
    if (t < 8) scal[t] = scl[t];
    if (b == 0) {
      if (t >= 8 && t < 72) Hz[t - 8] = 0.0f;
      if (t == 72) scl[4] = 0.0f;
      if (t == 73) scl[5] = 0.0f;
      if (t == 74) pHpd[it] = scl[0];
    }
    __syncthreads();
    const float pHp = scal[0], pp = scal[1], rp = scal[2], rz = scal[3];
    pgn2_r = scal[6];
    const bool bad  = pHp <= fmaxf(CG_REGf * pp, CG_REGf * pgn2_r);
    const bool stag = fabsf(rp) < 1e-30f;
    sc_r = bad || stag;
    const float alpha = sc_r ? 0.0f : rz / fmaxf(pHp, 1e-30f);
    if (valid) { t_ += alpha * p_; r_ -= alpha * hp_; }
    stage[t] = valid ? r_ : 0.0f;
    __syncthreads();
    for (int m = wv; m < M_; m += 4) {
      float s = 0.0f;
#pragma unroll
      for (int e0 = 0; e0 < BSZ; e0 += 64) {
        const int e = e0 + lane, col = base + e;
        const float av = (col < N_) ? A[(size_t)m * N_ + col] : 0.0f;
        s += av * stage[e];
      }
      s = wave_reduce_sum(s);
      if (lane == 0) atomicAdd(&yacc[m], s);
    }
    grid.sync();

    // ---- C: s = inv*y; z = r - A^T s; zz, rz_new; Hz = HP @ z; zero w/pp/rp ----
    if (t < 64) ysh[t] = yacc[t];
    if (b == 0) {
      if (t >= 64 && t < 128) wacc[t - 64] = 0.0f;
      if (t == 128) scl[1] = 0.0f;
      if (t == 129) scl[2] = 0.0f;
    }
    __syncthreads();
    if (t < 64) {
      float s = 0.0f;
#pragma unroll 8
      for (int j = 0; j < 64; ++j) s += inv[t * 64 + j] * ysh[j];
      ssh[t] = s;
    }
    __syncthreads();
    float zv = 0.0f;
    if (valid) {
      float acc = 0.0f;
#pragma unroll 8
      for (int m = 0; m < M_; ++m) acc += A[(size_t)m * N_ + i] * ssh[m];
      zv = r_ - acc;
    }
    z_ = zv;
    stage[t] = valid ? zv : 0.0f;
    {
      const float v1 = wave_reduce_sum(zv * zv);
      const float v2 = wave_reduce_sum(r_ * zv);
      if (lane == 0) { red[wv] = v1; red[4 + wv] = v2; }
      __syncthreads();
      if (t == 0) {
        atomicAdd(&scl[5], red[0] + red[1] + red[2] + red[3]);  // zz
        atomicAdd(&scl[4], red[4] + red[5] + red[6] + red[7]);  // rz_new
      }
    }
    for (int j = wv; j <= it; j += 4) {
      float s = 0.0f;
#pragma unroll
      for (int e0 = 0; e0 < BSZ; e0 += 64) {
        const int e = e0 + lane, col = base + e;
        const float hv = (col < N_) ? HPb[(size_t)j * N_ + col] : 0.0f;
        s += hv * stage[e];
      }
      s = wave_reduce_sum(s);
      if (lane == 0) atomicAdd(&Hz[j], s);
    }
    grid.sync();

    // ---- D: coeffs; p_new = z - coeffs@P; pp, rp; w = U^T p_new; conv/rz; zero pHp ----
    if (t < 64) {
      float c = 0.0f;
      if (t <= it) {
        const float d = pHpd[t];
        const float ds = (fabsf(d) > 1e-30f) ? d : 1e-30f;
        c = Hz[t] / ds;
      }
      csh[t] = c;
    }
    if (b == 0 && t == 255) scl[0] = 0.0f;
    __syncthreads();
    float pn = zv;
    if (valid) {
      for (int j = 0; j <= it; ++j) pn -= csh[j] * Pb[(size_t)j * N_ + i];
    }
    p_ = pn;
    stage[t] = valid ? pn : 0.0f;
    {
      const float v1 = wave_reduce_sum(pn * pn);
      const float v2 = wave_reduce_sum(r_ * pn);
      if (lane == 0) { red[wv] = v1; red[4 + wv] = v2; }
      __syncthreads();
      if (t == 0) {
        atomicAdd(&scl[1], red[0] + red[1] + red[2] + red[3]);  // pp
        atomicAdd(&scl[2], red[4] + red[5] + red[6] + red[7]);  // rp
      }
    }
    for (int k = wv; k < K_; k += 4) {
      float s = 0.0f;
#pragma unroll
      for (int e0 = 0; e0 < BSZ; e0 += 64) {
        const int e = e0 + lane, col = base + e;
        const float uv = (col < N_) ? Ut[(size_t)k * N_ + col] : 0.0f;
        s += uv * stage[e];
      }
      s = wave_reduce_sum(s);
      if (lane == 0) atomicAdd(&wacc[k], s);
    }
    if (b == 0 && t == 0) {
      const float zz = scl[5], rzn = scl[4];
      const float znorm = sqrtf(fmaxf(zz, 0.0f));
      const float tol = fmaxf(TOL_ABSf, CG_TOLf * sqrtf(fmaxf(pgn2_r, 0.0f)));
      if ((znorm <= tol) || sc_r)
        __hip_atomic_store(&scl[7], 1.0f, __ATOMIC_RELEASE, __HIP_MEMORY_SCOPE_AGENT);
      scl[3] = rzn;  // rz <- rz_new
    }
    grid.sync();
  }

  // ---------------- epilogue ----------------
  if (valid) out[i] = t_;
  if (b == 0 && t == 0) {
    out[N_]     = sqrtf(fmaxf(scl[6], 0.0f));
    out[N_ + 1] = (scl[7] != 0.0f) ? 1.0f : 0.0f;
  }
}

extern "C" void kernel_launch(void* const* d_in, const int* in_sizes, int n_in,
                              void* d_out, int out_size, void* d_ws, size_t ws_size,
                              hipStream_t stream) {
  (void)in_sizes; (void)n_in; (void)out_size; (void)ws_size;
  const float* g  = (const float*)d_in[0];
  const float* dg = (const float*)d_in[1];
  const float* U  = (const float*)d_in[2];
  const float* A  = (const float*)d_in[3];
  float* out = (float*)d_out;
  float* ws  = (float*)d_ws;
  void* args[] = {(void*)&g, (void*)&dg, (void*)&U, (void*)&A, (void*)&out, (void*)&ws};
  hipLaunchCooperativeKernel(stcg_kernel, dim3(NBLK), dim3(BSZ), args, 0, stream);
}